// Round 14
// baseline (433.322 us; speedup 1.0000x reference)
//
#include <hip/hip_runtime.h>
#include <math.h>

#define N_NODES 100000
#define IN_DIM  128
#define HIDDEN  64
#define N_EDGES 1600000

// ---------------------------------------------------------------------------
// R13 path A'' workspace (4-byte units), LINE-PADDED counts (R12 layout):
//   [0,       100000)   weights  (float)   per-node gate
//   [100000, 1700000)   counts   (int x16) one counter per 64B line: row*16
//   [1700000,1800000)   base     (int)     per-node segment base in bucket
//   [1800000,3400000)   bucket   (int)     edge source (col) grouped by row
//   [3400000,9800000)   x_bf16   (ushort)  RNE bf16 mirror of x
// Total 9,800,000 words = 39.2 MB (proven available: R9/R12 ran this path).
// rank[e] scratch lives in the OUT buffer (consumed by fill BEFORE the fused
// gather_prompt kernel writes out).
//
// Atomic-phase evidence ledger (CLOSED — ~110 us is a structural floor):
//   R5  fill w/ cursor atomics:   117 us, VALU 0.4%
//   R7  fill atomic-free:         ~52 us  (-65)
//   R8  hist 1/thread:            117 us
//   R9  hist + dependent store:   197 us  (chain length doubles time)
//   R10 hist x4/thread:           129-143 us (batching hurts)
//   R12 hist line-padded:         113 us  (null)
// => 1.6M scattered device atomics ~14.5 G/s regardless of ILP/layout.
//    gate+conv hide under it; stop optimizing this phase.
//
// R13: fuse gather+prompt through LDS — kills the 100 MB readout round-trip
// (gather wrote 50 MB that prompt re-read) and overlaps prompt's VALU with
// gather's memory stalls across blocks.
// ---------------------------------------------------------------------------
#define CSTRIDE     16
#define WS3_WEIGHTS 0
#define WS3_COUNTS  100000
#define WS3_BASE    1700000
#define WS3_BUCKET  1800000
#define WS3_XBF16   3400000
#define WS3_TOTAL   9800000            // 39.2 MB

// Legacy R8 layout (path A fallback, 33.6 MB — verified):
#define WS_WEIGHTS 0
#define WS_COUNTS  100000
#define WS_CURSOR  200000
#define WS_COUNTER 300000
#define WS_BASE    300016
#define WS_BUCKET  400016
#define WS_XBF16   2000016
#define WS_TOTAL   2000016             // path B requirement
#define WS_TOTAL2  (WS_XBF16 + 6400000)

#define NB_GATE  ((N_NODES + 63) / 64)               // 1563
#define NB_HIST  ((N_EDGES + 255) / 256)             // 6250 (1 edge/thread)
#define NB_FILL4 ((N_EDGES / 4 + 255) / 256)         // 1563 (4 edges/thread)
#define NB_CONV  ((N_NODES * IN_DIM / 8 + 255) / 256)// 6250 (exact)

__global__ __launch_bounds__(256) void zero_f4_kernel(float4* __restrict__ p, int n4)
{
    const int i = blockIdx.x * 256 + threadIdx.x;
    if (i < n4) p[i] = make_float4(0.f, 0.f, 0.f, 0.f);
}

__device__ __forceinline__ unsigned int bf16_rne(float f)
{
    const unsigned int u = __float_as_uint(f);
    return (u + 0x7FFFu + ((u >> 16) & 1u)) >> 16;
}

// ---------------------------------------------------------------------------
// Gate body (v6, verified).
// ---------------------------------------------------------------------------
__device__ __forceinline__ void gate_body(
    int gblock,
    const float* __restrict__ x, const float* __restrict__ W_sim,
    const float* __restrict__ b_sim, const float* __restrict__ w_vec,
    const float* __restrict__ b_vec, float* __restrict__ weights)
{
    __shared__ float part[4][64];
    const int lane  = threadIdx.x & 63;
    const int w     = __builtin_amdgcn_readfirstlane(threadIdx.x >> 6);
    const int jb    = 16 * w;
    const int node  = gblock * 64 + lane;
    const bool valid = node < N_NODES;
    const float4* xr = (const float4*)(x + (size_t)(valid ? node : 0) * IN_DIM);

    float acc[16];
#pragma unroll
    for (int j = 0; j < 16; ++j) acc[j] = b_sim[jb + j];

    for (int k4 = 0; k4 < IN_DIM / 4; ++k4) {
        const float4 a = xr[k4];
#pragma unroll
        for (int j = 0; j < 16; ++j) {
            acc[j] += a.x * W_sim[(4 * k4 + 0) * HIDDEN + jb + j];
            acc[j] += a.y * W_sim[(4 * k4 + 1) * HIDDEN + jb + j];
            acc[j] += a.z * W_sim[(4 * k4 + 2) * HIDDEN + jb + j];
            acc[j] += a.w * W_sim[(4 * k4 + 3) * HIDDEN + jb + j];
        }
    }

    float p = 0.f;
#pragma unroll
    for (int j = 0; j < 16; ++j)
        p += tanhf(acc[j]) * w_vec[jb + j];

    part[w][lane] = p;
    __syncthreads();

    if (threadIdx.x < 64) {
        const float g = part[0][lane] + part[1][lane] + part[2][lane] + part[3][lane];
        if (valid)
            weights[node] = 1.f / (1.f + expf(-(g + b_vec[0])));
    }
}

__global__ __launch_bounds__(256) void gate_kernel(
    const float* __restrict__ x, const float* __restrict__ W_sim,
    const float* __restrict__ b_sim, const float* __restrict__ w_vec,
    const float* __restrict__ b_vec, float* __restrict__ weights)
{
    gate_body(blockIdx.x, x, W_sim, b_sim, w_vec, b_vec, weights);
}

// ---------------------------------------------------------------------------
// R12 fused gate + hist(1/thread, line-padded counts) + conv (verified).
// ---------------------------------------------------------------------------
__global__ __launch_bounds__(256) void gate_hist_conv_p_kernel(
    const float* __restrict__ x, const float* __restrict__ W_sim,
    const float* __restrict__ b_sim, const float* __restrict__ w_vec,
    const float* __restrict__ b_vec, float* __restrict__ weights,
    const int* __restrict__ edge_index, int* __restrict__ counts /* padded */,
    int* __restrict__ rank /* = out buffer scratch */,
    unsigned int* __restrict__ xb16)
{
    if (blockIdx.x < NB_HIST) {
        const int e = blockIdx.x * 256 + threadIdx.x;
        if (e < N_EDGES) {
            const int row = edge_index[e];
            rank[e] = atomicAdd(&counts[row << 4], 1);
        }
        return;
    }
    if (blockIdx.x < NB_HIST + NB_CONV) {
        const int t = (blockIdx.x - NB_HIST) * 256 + threadIdx.x;
        const float4* src = (const float4*)x;
        const float4 a = src[2 * t + 0];
        const float4 b = src[2 * t + 1];
        uint4 o;
        o.x = bf16_rne(a.x) | (bf16_rne(a.y) << 16);
        o.y = bf16_rne(a.z) | (bf16_rne(a.w) << 16);
        o.z = bf16_rne(b.x) | (bf16_rne(b.y) << 16);
        o.w = bf16_rne(b.z) | (bf16_rne(b.w) << 16);
        ((uint4*)xb16)[t] = o;
        return;
    }
    gate_body(blockIdx.x - NB_HIST - NB_CONV, x, W_sim, b_sim, w_vec, b_vec, weights);
}

__global__ __launch_bounds__(256) void alloc_p_kernel(
    const int* __restrict__ counts /* padded */, int* __restrict__ base,
    int* __restrict__ counter)
{
    const int node = blockIdx.x * 256 + threadIdx.x;
    const int lane = threadIdx.x & 63;
    const int c = (node < N_NODES) ? counts[node << 4] : 0;

    int incl = c;
#pragma unroll
    for (int off = 1; off < 64; off <<= 1) {
        int v = __shfl_up(incl, off, 64);
        if (lane >= off) incl += v;
    }
    const int excl = incl - c;
    int wbase = 0;
    if (lane == 63) wbase = atomicAdd(counter, incl);
    wbase = __shfl(wbase, 63, 64);

    if (node < N_NODES) base[node] = wbase + excl;
}

// ---------------------------------------------------------------------------
// Fill (R10 x4 form, atomic-free, verified).
// ---------------------------------------------------------------------------
__global__ __launch_bounds__(256) void fill_kernel(
    const int* __restrict__ edge_index, const int* __restrict__ base,
    const int* __restrict__ rank, int* __restrict__ bucket)
{
    const int t4 = blockIdx.x * 256 + threadIdx.x;
    if (t4 * 4 >= N_EDGES) return;
    const int4 rows = ((const int4*)edge_index)[t4];
    const int4 cols = ((const int4*)(edge_index + N_EDGES))[t4];
    const int4 rk   = ((const int4*)rank)[t4];
    const int b0 = base[rows.x];
    const int b1 = base[rows.y];
    const int b2 = base[rows.z];
    const int b3 = base[rows.w];
    bucket[b0 + rk.x] = cols.x;
    bucket[b1 + rk.y] = cols.y;
    bucket[b2 + rk.z] = cols.z;
    bucket[b3 + rk.w] = cols.w;
}

// ---------------------------------------------------------------------------
// R13 FUSED gather + prompt (path A'').
// Phase 1 (gather): wave w fills LDS rows [16w,16w+16) — per row, the R8
//   half-split bf16 inner loop accumulates the weighted neighbor sum; half 0
//   writes the float4 straight into rb (no global round trip).
// Phase 2-4: prompt v9's verified MLP on rb (layer1 -> h in rb -> layer2 ->
//   prompts in rb), then ONE coalesced store out = x + prompts.
// Safety: rank (out scratch) was consumed by fill before this kernel; rb rows
//   of node>=N_NODES stay garbage (last block, waves 2-3 break early) but
//   each lane reads only its OWN row and the final store is FTOT-guarded —
//   garbage never reaches memory; m=0 rows write zeros.
// LDS 33.8 KB -> 4 blocks/CU (~50% occ); gather keeps 4 indep load chains
//   per wave (2 per half) — enough in-flight bytes at 16 waves/CU.
// ---------------------------------------------------------------------------
#define RB_STRIDE 132
__global__ __launch_bounds__(256) void gather_prompt_kernel(
    const unsigned short* __restrict__ xb, const float* __restrict__ weights,
    const int* __restrict__ counts /* padded */, const int* __restrict__ base,
    const int* __restrict__ bucket, const float* __restrict__ x,
    float* __restrict__ out,
    const float* __restrict__ W1, const float* __restrict__ b1,
    const float* __restrict__ W2, const float* __restrict__ b2)
{
    __shared__ float rb[64 * RB_STRIDE];
    const int t    = threadIdx.x;
    const int lane = t & 63;
    const int w    = __builtin_amdgcn_readfirstlane(t >> 6);
    const int half = lane >> 5;
    const int l32  = lane & 31;
    const int jb   = 16 * w;   // layer1 h-col base  (HIDDEN/4 = 16)
    const int ob   = 32 * w;   // layer2 out-col base (IN_DIM/4 = 32)
    const int fbase = blockIdx.x * 2048;
    const int FTOT  = N_NODES * (IN_DIM / 4);

    // ---- phase 1: gather 16 rows per wave into rb ----
    for (int i = 0; i < 16; ++i) {
        const int n    = w * 16 + i;                 // row in block (wave-uniform)
        const int node = blockIdx.x * 64 + n;
        if (node >= N_NODES) break;                  // wave-uniform exit
        const int m = counts[node << 4];
        const int b = base[node];
        const int m0  = (m + 1) >> 1;
        const int beg = half ? m0 : 0;
        const int end = half ? m  : m0;

        float4 acc0 = make_float4(0.f, 0.f, 0.f, 0.f);
        float4 acc1 = make_float4(0.f, 0.f, 0.f, 0.f);

#define BF2F(us) __uint_as_float(((unsigned int)(us)) << 16)
        int e = beg;
        for (; e + 2 <= end; e += 2) {
            const int c0 = bucket[b + e + 0];
            const int c1 = bucket[b + e + 1];
            const float w0 = weights[c0];
            const float w1 = weights[c1];
            const ushort4 v0 = ((const ushort4*)(xb + (size_t)c0 * IN_DIM))[l32];
            const ushort4 v1 = ((const ushort4*)(xb + (size_t)c1 * IN_DIM))[l32];
            acc0.x += BF2F(v0.x) * w0; acc0.y += BF2F(v0.y) * w0;
            acc0.z += BF2F(v0.z) * w0; acc0.w += BF2F(v0.w) * w0;
            acc1.x += BF2F(v1.x) * w1; acc1.y += BF2F(v1.y) * w1;
            acc1.z += BF2F(v1.z) * w1; acc1.w += BF2F(v1.w) * w1;
        }
        if (e < end) {
            const int c = bucket[b + e];
            const float wv = weights[c];
            const ushort4 v = ((const ushort4*)(xb + (size_t)c * IN_DIM))[l32];
            acc0.x += BF2F(v.x) * wv; acc0.y += BF2F(v.y) * wv;
            acc0.z += BF2F(v.z) * wv; acc0.w += BF2F(v.w) * wv;
        }
#undef BF2F
        acc0.x += acc1.x; acc0.y += acc1.y; acc0.z += acc1.z; acc0.w += acc1.w;

        acc0.x += __shfl(acc0.x, lane ^ 32, 64);
        acc0.y += __shfl(acc0.y, lane ^ 32, 64);
        acc0.z += __shfl(acc0.z, lane ^ 32, 64);
        acc0.w += __shfl(acc0.w, lane ^ 32, 64);

        if (half == 0)
            *(float4*)&rb[n * RB_STRIDE + l32 * 4] = acc0;
    }
    __syncthreads();

    // ---- phase 2: layer1 (thread = node lane, h-cols jb..jb+16) ----
    float acc[16];
#pragma unroll
    for (int j = 0; j < 16; ++j) acc[j] = b1[jb + j];

    for (int k4 = 0; k4 < IN_DIM / 4; ++k4) {
        const float4 a = *(const float4*)&rb[lane * RB_STRIDE + 4 * k4];
#pragma unroll
        for (int j = 0; j < 16; ++j) {
            acc[j] += a.x * W1[(4 * k4 + 0) * HIDDEN + jb + j];
            acc[j] += a.y * W1[(4 * k4 + 1) * HIDDEN + jb + j];
            acc[j] += a.z * W1[(4 * k4 + 2) * HIDDEN + jb + j];
            acc[j] += a.w * W1[(4 * k4 + 3) * HIDDEN + jb + j];
        }
    }
    __syncthreads();   // all row reads done before h overwrites rb

#pragma unroll
    for (int q = 0; q < 4; ++q) {
        float4 hv;
        hv.x = fmaxf(acc[4 * q + 0], 0.f);
        hv.y = fmaxf(acc[4 * q + 1], 0.f);
        hv.z = fmaxf(acc[4 * q + 2], 0.f);
        hv.w = fmaxf(acc[4 * q + 3], 0.f);
        *(float4*)&rb[lane * RB_STRIDE + jb + 4 * q] = hv;
    }
    __syncthreads();

    // ---- phase 3: layer2 (thread = node lane, out-cols ob..ob+32) ----
    float acc2[32];
#pragma unroll
    for (int jj = 0; jj < 32; ++jj) acc2[jj] = b2[ob + jj];
#pragma unroll
    for (int q = 0; q < 16; ++q) {
        const float4 h4 = *(const float4*)&rb[lane * RB_STRIDE + 4 * q];
#pragma unroll
        for (int jj = 0; jj < 32; ++jj)
            acc2[jj] += h4.x * W2[(4 * q + 0) * IN_DIM + ob + jj];
#pragma unroll
        for (int jj = 0; jj < 32; ++jj)
            acc2[jj] += h4.y * W2[(4 * q + 1) * IN_DIM + ob + jj];
#pragma unroll
        for (int jj = 0; jj < 32; ++jj)
            acc2[jj] += h4.z * W2[(4 * q + 2) * IN_DIM + ob + jj];
#pragma unroll
        for (int jj = 0; jj < 32; ++jj)
            acc2[jj] += h4.w * W2[(4 * q + 3) * IN_DIM + ob + jj];
    }
    __syncthreads();   // all h reads done before prompts overwrite rb

#pragma unroll
    for (int q = 0; q < 8; ++q) {
        float4 pv;
        pv.x = acc2[4 * q + 0];
        pv.y = acc2[4 * q + 1];
        pv.z = acc2[4 * q + 2];
        pv.w = acc2[4 * q + 3];
        *(float4*)&rb[lane * RB_STRIDE + ob + 4 * q] = pv;
    }
    __syncthreads();

    // ---- phase 4: ONE coalesced store out = x + prompts ----
    const float4* x4 = (const float4*)x;
    float4* o4 = (float4*)out;
#pragma unroll
    for (int i = 0; i < 8; ++i) {
        const int f = t + i * 256;
        if (fbase + f < FTOT) {
            const int row = f >> 5, c4 = f & 31;
            const float4 pv = *(const float4*)&rb[row * RB_STRIDE + c4 * 4];
            const float4 xv = x4[fbase + f];
            float4 ov;
            ov.x = xv.x + pv.x;
            ov.y = xv.y + pv.y;
            ov.z = xv.z + pv.z;
            ov.w = xv.w + pv.w;
            o4[fbase + f] = ov;
        }
    }
}

// ===========================================================================
// Legacy path kernels (A 33.6MB / B / C fallbacks — verified earlier rounds).
// ===========================================================================
__global__ __launch_bounds__(256) void gate_hist_conv_kernel(
    const float* __restrict__ x, const float* __restrict__ W_sim,
    const float* __restrict__ b_sim, const float* __restrict__ w_vec,
    const float* __restrict__ b_vec, float* __restrict__ weights,
    const int* __restrict__ edge_index, int* __restrict__ counts,
    int* __restrict__ rank, unsigned int* __restrict__ xb16)
{
    if (blockIdx.x < NB_CONV) {
        const int t = blockIdx.x * 256 + threadIdx.x;
        const float4* src = (const float4*)x;
        const float4 a = src[2 * t + 0];
        const float4 b = src[2 * t + 1];
        uint4 o;
        o.x = bf16_rne(a.x) | (bf16_rne(a.y) << 16);
        o.y = bf16_rne(a.z) | (bf16_rne(a.w) << 16);
        o.z = bf16_rne(b.x) | (bf16_rne(b.y) << 16);
        o.w = bf16_rne(b.z) | (bf16_rne(b.w) << 16);
        ((uint4*)xb16)[t] = o;
        return;
    }
    if (blockIdx.x < NB_CONV + NB_HIST) {
        const int e = (blockIdx.x - NB_CONV) * 256 + threadIdx.x;
        if (e < N_EDGES) {
            const int row = edge_index[e];
            rank[e] = atomicAdd(&counts[row], 1);
        }
        return;
    }
    gate_body(blockIdx.x - NB_CONV - NB_HIST, x, W_sim, b_sim, w_vec, b_vec, weights);
}

__global__ __launch_bounds__(256) void gate_hist_kernel(
    const float* __restrict__ x, const float* __restrict__ W_sim,
    const float* __restrict__ b_sim, const float* __restrict__ w_vec,
    const float* __restrict__ b_vec, float* __restrict__ weights,
    const int* __restrict__ edge_index, int* __restrict__ counts,
    int* __restrict__ rank)
{
    if (blockIdx.x < NB_HIST) {
        const int e = blockIdx.x * 256 + threadIdx.x;
        if (e < N_EDGES) {
            const int row = edge_index[e];
            rank[e] = atomicAdd(&counts[row], 1);
        }
        return;
    }
    gate_body(blockIdx.x - NB_HIST, x, W_sim, b_sim, w_vec, b_vec, weights);
}

__global__ __launch_bounds__(256) void alloc_kernel(
    const int* __restrict__ counts, int* __restrict__ base, int* __restrict__ counter)
{
    const int node = blockIdx.x * 256 + threadIdx.x;
    const int lane = threadIdx.x & 63;
    const int c = (node < N_NODES) ? counts[node] : 0;

    int incl = c;
#pragma unroll
    for (int off = 1; off < 64; off <<= 1) {
        int v = __shfl_up(incl, off, 64);
        if (lane >= off) incl += v;
    }
    const int excl = incl - c;
    int wbase = 0;
    if (lane == 63) wbase = atomicAdd(counter, incl);
    wbase = __shfl(wbase, 63, 64);

    if (node < N_NODES) base[node] = wbase + excl;
}

__global__ __launch_bounds__(256) void gather_bf16_kernel(
    const unsigned short* __restrict__ xb, const float* __restrict__ weights,
    const int* __restrict__ counts, const int* __restrict__ base,
    const int* __restrict__ bucket, float* __restrict__ readout)
{
    const int wave = threadIdx.x >> 6;
    const int lane = threadIdx.x & 63;
    const int half = lane >> 5;
    const int l32  = lane & 31;
    const int node = blockIdx.x * 4 + wave;
    if (node >= N_NODES) return;

    const int m = counts[node];
    const int b = base[node];
    const int m0  = (m + 1) >> 1;
    const int beg = half ? m0 : 0;
    const int end = half ? m  : m0;

    float4 acc0 = make_float4(0.f, 0.f, 0.f, 0.f);
    float4 acc1 = make_float4(0.f, 0.f, 0.f, 0.f);

#define BF2F(us) __uint_as_float(((unsigned int)(us)) << 16)
    int i = beg;
    for (; i + 2 <= end; i += 2) {
        const int c0 = bucket[b + i + 0];
        const int c1 = bucket[b + i + 1];
        const float w0 = weights[c0];
        const float w1 = weights[c1];
        const ushort4 v0 = ((const ushort4*)(xb + (size_t)c0 * IN_DIM))[l32];
        const ushort4 v1 = ((const ushort4*)(xb + (size_t)c1 * IN_DIM))[l32];
        acc0.x += BF2F(v0.x) * w0; acc0.y += BF2F(v0.y) * w0;
        acc0.z += BF2F(v0.z) * w0; acc0.w += BF2F(v0.w) * w0;
        acc1.x += BF2F(v1.x) * w1; acc1.y += BF2F(v1.y) * w1;
        acc1.z += BF2F(v1.z) * w1; acc1.w += BF2F(v1.w) * w1;
    }
    if (i < end) {
        const int c = bucket[b + i];
        const float wv = weights[c];
        const ushort4 v = ((const ushort4*)(xb + (size_t)c * IN_DIM))[l32];
        acc0.x += BF2F(v.x) * wv; acc0.y += BF2F(v.y) * wv;
        acc0.z += BF2F(v.z) * wv; acc0.w += BF2F(v.w) * wv;
    }
#undef BF2F
    acc0.x += acc1.x; acc0.y += acc1.y; acc0.z += acc1.z; acc0.w += acc1.w;

    acc0.x += __shfl(acc0.x, lane ^ 32, 64);
    acc0.y += __shfl(acc0.y, lane ^ 32, 64);
    acc0.z += __shfl(acc0.z, lane ^ 32, 64);
    acc0.w += __shfl(acc0.w, lane ^ 32, 64);

    if (half == 0)
        ((float4*)(readout + (size_t)node * IN_DIM))[l32] = acc0;
}

__global__ __launch_bounds__(256) void gather_kernel(
    const float* __restrict__ x, const float* __restrict__ weights,
    const int* __restrict__ counts, const int* __restrict__ base,
    const int* __restrict__ bucket, float* __restrict__ readout)
{
    const int wave = threadIdx.x >> 6;
    const int lane = threadIdx.x & 63;
    const int half = lane >> 5;
    const int l32  = lane & 31;
    const int node = blockIdx.x * 4 + wave;
    if (node >= N_NODES) return;

    const int m = counts[node];
    const int b = base[node];
    const int m0  = (m + 1) >> 1;
    const int beg = half ? m0 : 0;
    const int end = half ? m  : m0;

    float4 acc0 = make_float4(0.f, 0.f, 0.f, 0.f);
    float4 acc1 = make_float4(0.f, 0.f, 0.f, 0.f);

    int i = beg;
    for (; i + 2 <= end; i += 2) {
        const int c0 = bucket[b + i + 0];
        const int c1 = bucket[b + i + 1];
        const float w0 = weights[c0];
        const float w1 = weights[c1];
        const float4 r0 = ((const float4*)(x + (size_t)c0 * IN_DIM))[l32];
        const float4 r1 = ((const float4*)(x + (size_t)c1 * IN_DIM))[l32];
        acc0.x += r0.x * w0; acc0.y += r0.y * w0; acc0.z += r0.z * w0; acc0.w += r0.w * w0;
        acc1.x += r1.x * w1; acc1.y += r1.y * w1; acc1.z += r1.z * w1; acc1.w += r1.w * w1;
    }
    if (i < end) {
        const int c = bucket[b + i];
        const float wv = weights[c];
        const float4 r = ((const float4*)(x + (size_t)c * IN_DIM))[l32];
        acc0.x += r.x * wv; acc0.y += r.y * wv; acc0.z += r.z * wv; acc0.w += r.w * wv;
    }
    acc0.x += acc1.x; acc0.y += acc1.y; acc0.z += acc1.z; acc0.w += acc1.w;

    acc0.x += __shfl(acc0.x, lane ^ 32, 64);
    acc0.y += __shfl(acc0.y, lane ^ 32, 64);
    acc0.z += __shfl(acc0.z, lane ^ 32, 64);
    acc0.w += __shfl(acc0.w, lane ^ 32, 64);

    if (half == 0)
        ((float4*)(readout + (size_t)node * IN_DIM))[l32] = acc0;
}

__global__ __launch_bounds__(256) void scatter_kernel(
    const float* __restrict__ x, const int* __restrict__ edge_index,
    const float* __restrict__ weights, float* __restrict__ readout)
{
    const int gid = blockIdx.x * 256 + threadIdx.x;
    const int e = gid >> 5;
    const int c = gid & 31;
    if (e >= N_EDGES) return;
    const int row = edge_index[e];
    const int col = edge_index[N_EDGES + e];
    const float w = weights[col];
    const float4 xv = ((const float4*)(x + (size_t)col * IN_DIM))[c];
    float* dst = readout + (size_t)row * IN_DIM + c * 4;
    atomicAdd(dst + 0, xv.x * w);
    atomicAdd(dst + 1, xv.y * w);
    atomicAdd(dst + 2, xv.z * w);
    atomicAdd(dst + 3, xv.w * w);
}

// ---------------------------------------------------------------------------
// Prompt v9 (legacy paths A/B/C — verified R12).
// ---------------------------------------------------------------------------
__global__ __launch_bounds__(256) void prompt_kernel(
    const float* __restrict__ x, float* __restrict__ out /* = readout */,
    const float* __restrict__ W1, const float* __restrict__ b1,
    const float* __restrict__ W2, const float* __restrict__ b2)
{
    __shared__ float rb[64 * RB_STRIDE];
    const int t    = threadIdx.x;
    const int lane = t & 63;
    const int w    = __builtin_amdgcn_readfirstlane(t >> 6);
    const int jb   = 16 * w;
    const int ob   = 32 * w;
    const int fbase = blockIdx.x * 2048;
    const int FTOT  = N_NODES * (IN_DIM / 4);

    const float4* out4c = (const float4*)out;
#pragma unroll
    for (int i = 0; i < 8; ++i) {
        const int f = t + i * 256;
        if (fbase + f < FTOT) {
            const int row = f >> 5, c4 = f & 31;
            *(float4*)&rb[row * RB_STRIDE + c4 * 4] = out4c[fbase + f];
        }
    }
    __syncthreads();

    float acc[16];
#pragma unroll
    for (int j = 0; j < 16; ++j) acc[j] = b1[jb + j];

    for (int k4 = 0; k4 < IN_DIM / 4; ++k4) {
        const float4 a = *(const float4*)&rb[lane * RB_STRIDE + 4 * k4];
#pragma unroll
        for (int j = 0; j < 16; ++j) {
            acc[j] += a.x * W1[(4 * k4 + 0) * HIDDEN + jb + j];
            acc[j] += a.y * W1[(4 * k4 + 1) * HIDDEN + jb + j];
            acc[j] += a.z * W1[(4 * k4 + 2) * HIDDEN + jb + j];
            acc[j] += a.w * W1[(4 * k4 + 3) * HIDDEN + jb + j];
        }
    }
    __syncthreads();

#pragma unroll
    for (int q = 0; q < 4; ++q) {
        float4 hv;
        hv.x = fmaxf(acc[4 * q + 0], 0.f);
        hv.y = fmaxf(acc[4 * q + 1], 0.f);
        hv.z = fmaxf(acc[4 * q + 2], 0.f);
        hv.w = fmaxf(acc[4 * q + 3], 0.f);
        *(float4*)&rb[lane * RB_STRIDE + jb + 4 * q] = hv;
    }
    __syncthreads();

    float acc2[32];
#pragma unroll
    for (int jj = 0; jj < 32; ++jj) acc2[jj] = b2[ob + jj];
#pragma unroll
    for (int q = 0; q < 16; ++q) {
        const float4 h4 = *(const float4*)&rb[lane * RB_STRIDE + 4 * q];
#pragma unroll
        for (int jj = 0; jj < 32; ++jj)
            acc2[jj] += h4.x * W2[(4 * q + 0) * IN_DIM + ob + jj];
#pragma unroll
        for (int jj = 0; jj < 32; ++jj)
            acc2[jj] += h4.y * W2[(4 * q + 1) * IN_DIM + ob + jj];
#pragma unroll
        for (int jj = 0; jj < 32; ++jj)
            acc2[jj] += h4.z * W2[(4 * q + 2) * IN_DIM + ob + jj];
#pragma unroll
        for (int jj = 0; jj < 32; ++jj)
            acc2[jj] += h4.w * W2[(4 * q + 3) * IN_DIM + ob + jj];
    }
    __syncthreads();

#pragma unroll
    for (int q = 0; q < 8; ++q) {
        float4 pv;
        pv.x = acc2[4 * q + 0];
        pv.y = acc2[4 * q + 1];
        pv.z = acc2[4 * q + 2];
        pv.w = acc2[4 * q + 3];
        *(float4*)&rb[lane * RB_STRIDE + ob + 4 * q] = pv;
    }
    __syncthreads();

    const float4* x4 = (const float4*)x;
    float4* o4 = (float4*)out;
#pragma unroll
    for (int i = 0; i < 8; ++i) {
        const int f = t + i * 256;
        if (fbase + f < FTOT) {
            const int row = f >> 5, c4 = f & 31;
            const float4 pv = *(const float4*)&rb[row * RB_STRIDE + c4 * 4];
            const float4 xv = x4[fbase + f];
            float4 ov;
            ov.x = xv.x + pv.x;
            ov.y = xv.y + pv.y;
            ov.z = xv.z + pv.z;
            ov.w = xv.w + pv.w;
            o4[fbase + f] = ov;
        }
    }
}

// ---------------------------------------------------------------------------
extern "C" void kernel_launch(void* const* d_in, const int* in_sizes, int n_in,
                              void* d_out, int out_size, void* d_ws, size_t ws_size,
                              hipStream_t stream)
{
    const float* x          = (const float*)d_in[0];
    const int*   edge_index = (const int*)d_in[1];   // int32 (JAX x64 disabled)
    const float* W_sim      = (const float*)d_in[2];
    const float* b_sim      = (const float*)d_in[3];
    const float* w_vec      = (const float*)d_in[4];
    const float* b_vec      = (const float*)d_in[5];
    const float* W1         = (const float*)d_in[6];
    const float* b1         = (const float*)d_in[7];
    const float* W2         = (const float*)d_in[8];
    const float* b2         = (const float*)d_in[9];

    float* out = (float*)d_out;
    float* wsf = (float*)d_ws;
    int*   wsi = (int*)d_ws;

    if (ws_size >= (size_t)WS3_TOTAL * 4) {
        // ------- Path A'' (R13): line-padded counts + fused gather+prompt ----
        float* weights = wsf + WS3_WEIGHTS;
        int* counts  = wsi + WS3_COUNTS;     // padded x16
        int* base    = wsi + WS3_BASE;
        int* bucket  = wsi + WS3_BUCKET;
        unsigned int*   xb16u = (unsigned int*)(wsi + WS3_XBF16);
        unsigned short* xb16  = (unsigned short*)xb16u;
        int* rank    = (int*)out;            // out dead until gather_prompt
        int* counter = &counts[CSTRIDE * N_NODES - 1];  // tail pad of node 99999

        hipMemsetAsync(counts, 0, (size_t)CSTRIDE * N_NODES * 4, stream);

        gate_hist_conv_p_kernel<<<NB_HIST + NB_CONV + NB_GATE, 256, 0, stream>>>(
            x, W_sim, b_sim, w_vec, b_vec, weights, edge_index, counts, rank, xb16u);
        alloc_p_kernel<<<(N_NODES + 255) / 256, 256, 0, stream>>>(counts, base, counter);
        fill_kernel<<<NB_FILL4, 256, 0, stream>>>(edge_index, base, rank, bucket);
        gather_prompt_kernel<<<NB_GATE, 256, 0, stream>>>(
            xb16, weights, counts, base, bucket, x, out, W1, b1, W2, b2);
        return;
    }

    float* weights = wsf + WS_WEIGHTS;
    if (ws_size >= (size_t)WS_TOTAL2 * 4) {
        // ------- Path A (R8, verified) -------
        int* counts  = wsi + WS_COUNTS;
        int* counter = wsi + WS_COUNTER;
        int* base    = wsi + WS_BASE;
        int* bucket  = wsi + WS_BUCKET;
        unsigned int*   xb16u = (unsigned int*)(wsi + WS_XBF16);
        unsigned short* xb16  = (unsigned short*)xb16u;
        int* rank    = (int*)out;

        hipMemsetAsync(wsi + WS_COUNTS, 0, (size_t)(WS_BASE - WS_COUNTS) * 4, stream);

        gate_hist_conv_kernel<<<NB_CONV + NB_HIST + NB_GATE, 256, 0, stream>>>(
            x, W_sim, b_sim, w_vec, b_vec, weights, edge_index, counts, rank, xb16u);
        alloc_kernel<<<(N_NODES + 255) / 256, 256, 0, stream>>>(counts, base, counter);
        fill_kernel<<<NB_FILL4, 256, 0, stream>>>(edge_index, base, rank, bucket);
        gather_bf16_kernel<<<N_NODES / 4, 256, 0, stream>>>(xb16, weights, counts, base, bucket, out);
    } else if (ws_size >= (size_t)WS_TOTAL * 4) {
        // ------- Path B (R7 structure, f32 gather) -------
        int* counts  = wsi + WS_COUNTS;
        int* counter = wsi + WS_COUNTER;
        int* base    = wsi + WS_BASE;
        int* bucket  = wsi + WS_BUCKET;
        int* rank    = (int*)out;

        hipMemsetAsync(wsi + WS_COUNTS, 0, (size_t)(WS_BASE - WS_COUNTS) * 4, stream);

        gate_hist_kernel<<<NB_HIST + NB_GATE, 256, 0, stream>>>(
            x, W_sim, b_sim, w_vec, b_vec, weights, edge_index, counts, rank);
        alloc_kernel<<<(N_NODES + 255) / 256, 256, 0, stream>>>(counts, base, counter);
        fill_kernel<<<NB_FILL4, 256, 0, stream>>>(edge_index, base, rank, bucket);
        gather_kernel<<<N_NODES / 4, 256, 0, stream>>>(x, weights, counts, base, bucket, out);
    } else {
        // ------- Path C: fallback scatter -------
        gate_kernel<<<NB_GATE, 256, 0, stream>>>(x, W_sim, b_sim, w_vec, b_vec, weights);
        const int n4 = N_NODES * IN_DIM / 4;
        zero_f4_kernel<<<(n4 + 255) / 256, 256, 0, stream>>>((float4*)out, n4);
        scatter_kernel<<<(N_EDGES * 32) / 256, 256, 0, stream>>>(x, edge_index, weights, out);
    }

    prompt_kernel<<<NB_GATE, 256, 0, stream>>>(x, out, W1, b1, W2, b2);
}